// Round 2
// baseline (971.877 us; speedup 1.0000x reference)
//
#include <hip/hip_runtime.h>

// LTC cell: out = states after 6 SDE unfolds of s += drift(s),
// drift = 6 ODE unfolds of v = (cm*v + gleak*vleak + num)/(cm + gleak + den),
// num/den = sums over presynaptic i of W*sigmoid(sigma*(v_i-mu))*{erev,1} + sensory terms.
//
// Design: VALU/transcendental-bound (1.21e9 sigmoid pairs). No MFMA possible
// (per-(i,j) nonlinearity before the reduction). Params packed as
// float4{A=-log2e*sigma, Bc=log2e*sigma*mu, W*erev, W} so the inner pair is:
// fma, v_exp_f32, add, v_rcp_f32, fma, fma (~24 wave-cyc/64 pairs).
// Block = 128 j-units x S=4 reduction splits = 512 thr; M=4 batch elems/thread
// amortizes L2 param reads (pp read once per block per ODE iter, 23 TB/s agg);
// v broadcast from LDS (wave-uniform = conflict-free); partials via LDS.

#define LOG2E 1.4426950408889634f

constexpr int U   = 128;
constexpr int I   = 64;
constexpr int B   = 2048;
constexpr int M   = 4;        // batch elements per block (per thread)
constexpr int S   = 4;        // i-reduction splits (across waves)
constexpr int BLK = U * S;    // 512 threads
constexpr int SDE = 6, ODE = 6;

#if __has_builtin(__builtin_amdgcn_exp2f)
#define EXP2(x) __builtin_amdgcn_exp2f(x)
#else
#define EXP2(x) exp2f(x)
#endif
#if __has_builtin(__builtin_amdgcn_rcpf)
#define RCP(x) __builtin_amdgcn_rcpf(x)
#else
#define RCP(x) (1.0f / (x))
#endif

// one sigmoid-accumulate pair: P = {A, Bc, W*erev, W}, V = presyn potential
#define SIGACC(P, V, PN, PD)                                   \
  {                                                            \
    float t_ = fmaf((P).x, (V), (P).y);                        \
    float e_ = EXP2(t_);                                       \
    float r_ = RCP(1.0f + e_);                                 \
    (PN) = fmaf((P).z, r_, (PN));                              \
    (PD) = fmaf((P).w, r_, (PD));                              \
  }

__global__ __launch_bounds__(256) void pack_params(
    const float* __restrict__ mu, const float* __restrict__ sigma,
    const float* __restrict__ W, const float* __restrict__ erev,
    const float* __restrict__ smu, const float* __restrict__ ssig,
    const float* __restrict__ sW, const float* __restrict__ serev,
    float4* __restrict__ pp, float4* __restrict__ ps)
{
  int idx = blockIdx.x * 256 + threadIdx.x;
  if (idx < U * U) {
    float sg = sigma[idx];
    float w  = W[idx];
    pp[idx] = make_float4(-LOG2E * sg, LOG2E * sg * mu[idx], w * erev[idx], w);
  } else if (idx < U * U + I * U) {
    int k = idx - U * U;
    float sg = ssig[k];
    float w  = sW[k];
    ps[k] = make_float4(-LOG2E * sg, LOG2E * sg * smu[k], w * serev[k], w);
  }
}

__global__ __launch_bounds__(BLK, 4) void ltc_kernel(
    const float4* __restrict__ pp, const float4* __restrict__ ps,
    const float* __restrict__ inputs, const float* __restrict__ states,
    const float* __restrict__ iw, const float* __restrict__ ibias,
    const float* __restrict__ vleak, const float* __restrict__ gleak,
    const float* __restrict__ cmt, float* __restrict__ out)
{
  __shared__ __align__(16) float v_lds[M][U];   // 2 KB, read as wave-uniform float4 (broadcast)
  __shared__ __align__(16) float x_lds[M][I];   // 1 KB
  __shared__ float2 part[S][M][U];              // 16 KB partial {num,den}

  const int tid = threadIdx.x;
  const int j   = tid & (U - 1);   // output unit
  const int s   = tid >> 7;        // i-reduction split id (uniform per wave)
  const int b0  = blockIdx.x * M;

  // per-unit scalars
  const float cm = cmt[j];
  const float gl = gleak[j];
  const float gv = gl * vleak[j];
  const float cg = cm + gl;

  // stage mapped input x = in*w + b into LDS
  if (tid < M * I) {
    const int m = tid >> 6, i = tid & (I - 1);
    x_lds[m][i] = inputs[(b0 + m) * I + i] * iw[i] + ibias[i];
  }
  __syncthreads();

  // ---- sensory terms (constant across all unfolds) ----
  float wns[M], wds[M];
  {
    float pn[M], pd[M];
#pragma unroll
    for (int m = 0; m < M; ++m) { pn[m] = 0.f; pd[m] = 0.f; }
#pragma unroll
    for (int ii = 0; ii < I / S; ii += 4) {
      const int i = s * (I / S) + ii;
      const float4 p0 = ps[(i + 0) * U + j];
      const float4 p1 = ps[(i + 1) * U + j];
      const float4 p2 = ps[(i + 2) * U + j];
      const float4 p3 = ps[(i + 3) * U + j];
#pragma unroll
      for (int m = 0; m < M; ++m) {
        const float4 xv = *reinterpret_cast<const float4*>(&x_lds[m][i]);
        SIGACC(p0, xv.x, pn[m], pd[m]);
        SIGACC(p1, xv.y, pn[m], pd[m]);
        SIGACC(p2, xv.z, pn[m], pd[m]);
        SIGACC(p3, xv.w, pn[m], pd[m]);
      }
    }
#pragma unroll
    for (int m = 0; m < M; ++m) part[s][m][j] = make_float2(pn[m], pd[m]);
    __syncthreads();
#pragma unroll
    for (int m = 0; m < M; ++m) {
      float n = 0.f, d = 0.f;
#pragma unroll
      for (int t2 = 0; t2 < S; ++t2) { const float2 f = part[t2][m][j]; n += f.x; d += f.y; }
      wns[m] = n; wds[m] = d;
    }
  }

  // load states
  float sv[M];
#pragma unroll
  for (int m = 0; m < M; ++m) sv[m] = states[(b0 + m) * U + j];

  float vj[M];
  for (int sde = 0; sde < SDE; ++sde) {
#pragma unroll
    for (int m = 0; m < M; ++m) vj[m] = sv[m];
    if (s == 0) {
#pragma unroll
      for (int m = 0; m < M; ++m) v_lds[m][j] = sv[m];
    }
    __syncthreads();  // covers v_lds publish + part reuse hazard

    for (int ode = 0; ode < ODE; ++ode) {
      float pn[M], pd[M];
#pragma unroll
      for (int m = 0; m < M; ++m) { pn[m] = 0.f; pd[m] = 0.f; }
#pragma unroll
      for (int ii = 0; ii < U / S; ii += 4) {
        const int i = s * (U / S) + ii;
        const float4 p0 = pp[(i + 0) * U + j];   // coalesced 1 KB/wave, L2-resident
        const float4 p1 = pp[(i + 1) * U + j];
        const float4 p2 = pp[(i + 2) * U + j];
        const float4 p3 = pp[(i + 3) * U + j];
#pragma unroll
        for (int m = 0; m < M; ++m) {
          const float4 vv = *reinterpret_cast<const float4*>(&v_lds[m][i]); // broadcast
          SIGACC(p0, vv.x, pn[m], pd[m]);
          SIGACC(p1, vv.y, pn[m], pd[m]);
          SIGACC(p2, vv.z, pn[m], pd[m]);
          SIGACC(p3, vv.w, pn[m], pd[m]);
        }
      }
#pragma unroll
      for (int m = 0; m < M; ++m) part[s][m][j] = make_float2(pn[m], pd[m]);
      __syncthreads();
      // every s-replica computes the identical v update (avoids a broadcast)
#pragma unroll
      for (int m = 0; m < M; ++m) {
        float n = wns[m], d = wds[m];
#pragma unroll
        for (int t2 = 0; t2 < S; ++t2) { const float2 f = part[t2][m][j]; n += f.x; d += f.y; }
        const float den = cg + d;
        float r = RCP(den);
        r = r * (2.0f - den * r);            // one Newton step: state-feedback path kept ~exact
        vj[m] = (fmaf(cm, vj[m], gv) + n) * r;
      }
      if (s == 0) {
#pragma unroll
        for (int m = 0; m < M; ++m) v_lds[m][j] = vj[m];
      }
      __syncthreads();  // v_lds ready for next i-sweep; part free for rewrite
    }
#pragma unroll
    for (int m = 0; m < M; ++m) sv[m] += vj[m];
  }

  if (s == 0) {
#pragma unroll
    for (int m = 0; m < M; ++m) out[(b0 + m) * U + j] = sv[m];
  }
}

extern "C" void kernel_launch(void* const* d_in, const int* in_sizes, int n_in,
                              void* d_out, int out_size, void* d_ws, size_t ws_size,
                              hipStream_t stream) {
  const float* inputs = (const float*)d_in[0];
  const float* states = (const float*)d_in[1];
  const float* iw     = (const float*)d_in[2];
  const float* ibias  = (const float*)d_in[3];
  const float* smu    = (const float*)d_in[4];
  const float* ssig   = (const float*)d_in[5];
  const float* sW     = (const float*)d_in[6];
  const float* serev  = (const float*)d_in[7];
  const float* mu     = (const float*)d_in[8];
  const float* sigma  = (const float*)d_in[9];
  const float* W      = (const float*)d_in[10];
  const float* erev   = (const float*)d_in[11];
  const float* vleak  = (const float*)d_in[12];
  const float* gleak  = (const float*)d_in[13];
  const float* cmt    = (const float*)d_in[14];
  float* out = (float*)d_out;

  // d_ws layout: packed main params (256 KB) then packed sensory params (128 KB)
  float4* pp = (float4*)d_ws;
  float4* ps = pp + U * U;

  const int packN = U * U + I * U;  // 24576
  pack_params<<<(packN + 255) / 256, 256, 0, stream>>>(
      mu, sigma, W, erev, smu, ssig, sW, serev, pp, ps);
  ltc_kernel<<<B / M, BLK, 0, stream>>>(
      pp, ps, inputs, states, iw, ibias, vleak, gleak, cmt, out);
}

// Round 3
// 358.747 us; speedup vs baseline: 2.7091x; 2.7091x over previous
//
#include <hip/hip_runtime.h>

// LTC cell: out = states after 6 SDE unfolds of s += drift(s),
// drift = 6 ODE unfolds of v = (cm*v + gleak*vleak + num)/(cm + gleak + den).
//
// Round-2 post-mortem: VGPR_Count=64 -> compiler spilled the working set to
// scratch inside the 36-iter loop (741 MB/dispatch writes + share of 2.9 GB
// fetch), VALUBusy 27%. Fix: params live in REGISTERS (32 float4/thread =
// 128 VGPRs, loaded once, zero global loads in main loop) and
// __launch_bounds__(512,2) to allow up to 256 VGPRs (no spill regime).
// Kernel is then VALU/transcendental-bound: ~24 wave-cyc per 64 sigmoid pairs,
// 1.21e9 pairs -> ~185 us floor; predict 240-320 us with barriers/reduction.

#define LOG2E 1.4426950408889634f

constexpr int U   = 128;
constexpr int I   = 64;
constexpr int B   = 2048;
constexpr int M   = 4;        // batch elements per block (per thread)
constexpr int S   = 4;        // i-reduction splits (across waves)
constexpr int BLK = U * S;    // 512 threads
constexpr int RPT = U / S;    // 32 param rows held in registers per thread
constexpr int SDE = 6, ODE = 6;

#if __has_builtin(__builtin_amdgcn_exp2f)
#define EXP2(x) __builtin_amdgcn_exp2f(x)
#else
#define EXP2(x) exp2f(x)
#endif
#if __has_builtin(__builtin_amdgcn_rcpf)
#define RCP(x) __builtin_amdgcn_rcpf(x)
#else
#define RCP(x) (1.0f / (x))
#endif

// one sigmoid-accumulate pair: P = {A=-log2e*sigma, Bc=log2e*sigma*mu, W*erev, W}
#define SIGACC(P, V, PN, PD)                                   \
  {                                                            \
    float t_ = fmaf((P).x, (V), (P).y);                        \
    float e_ = EXP2(t_);                                       \
    float r_ = RCP(1.0f + e_);                                 \
    (PN) = fmaf((P).z, r_, (PN));                              \
    (PD) = fmaf((P).w, r_, (PD));                              \
  }

__global__ __launch_bounds__(256) void pack_params(
    const float* __restrict__ mu, const float* __restrict__ sigma,
    const float* __restrict__ W, const float* __restrict__ erev,
    const float* __restrict__ smu, const float* __restrict__ ssig,
    const float* __restrict__ sW, const float* __restrict__ serev,
    float4* __restrict__ pp, float4* __restrict__ ps)
{
  int idx = blockIdx.x * 256 + threadIdx.x;
  if (idx < U * U) {
    float sg = sigma[idx];
    float w  = W[idx];
    pp[idx] = make_float4(-LOG2E * sg, LOG2E * sg * mu[idx], w * erev[idx], w);
  } else if (idx < U * U + I * U) {
    int k = idx - U * U;
    float sg = ssig[k];
    float w  = sW[k];
    ps[k] = make_float4(-LOG2E * sg, LOG2E * sg * smu[k], w * serev[k], w);
  }
}

__global__ __launch_bounds__(BLK, 2) void ltc_kernel(
    const float4* __restrict__ pp, const float4* __restrict__ ps,
    const float* __restrict__ inputs, const float* __restrict__ states,
    const float* __restrict__ iw, const float* __restrict__ ibias,
    const float* __restrict__ vleak, const float* __restrict__ gleak,
    const float* __restrict__ cmt, float* __restrict__ out)
{
  __shared__ __align__(16) float v_lds[M][U];   // wave-uniform float4 broadcast reads
  __shared__ __align__(16) float x_lds[M][I];
  __shared__ float2 part[S][M][U];              // 16 KB partial {num,den}

  const int tid = threadIdx.x;
  const int j   = tid & (U - 1);   // output unit
  const int s   = tid >> 7;        // i-split id (uniform per wave)
  const int b0  = blockIdx.x * M;

  const float cm = cmt[j];
  const float gl = gleak[j];
  const float gv = gl * vleak[j];
  const float cg = cm + gl;

  // ---- stage this thread's param column into REGISTERS (once) ----
  // thread (j,s) owns rows i in [s*32, s*32+32): 32 x float4 = 128 VGPRs.
  // Each load instr: 64 lanes read 64 consecutive float4 -> fully coalesced.
  float4 P[RPT];
#pragma unroll
  for (int k = 0; k < RPT; ++k) P[k] = pp[(s * RPT + k) * U + j];

  // stage mapped input x = in*w + b into LDS
  if (tid < M * I) {
    const int m = tid >> 6, i = tid & (I - 1);
    x_lds[m][i] = inputs[(b0 + m) * I + i] * iw[i] + ibias[i];
  }
  __syncthreads();

  // ---- sensory terms (constant across all unfolds; global ps reads, once) ----
  float wns[M], wds[M];
  {
    float pn[M], pd[M];
#pragma unroll
    for (int m = 0; m < M; ++m) { pn[m] = 0.f; pd[m] = 0.f; }
#pragma unroll
    for (int ii = 0; ii < I / S; ii += 4) {
      const int i = s * (I / S) + ii;
      const float4 p0 = ps[(i + 0) * U + j];
      const float4 p1 = ps[(i + 1) * U + j];
      const float4 p2 = ps[(i + 2) * U + j];
      const float4 p3 = ps[(i + 3) * U + j];
#pragma unroll
      for (int m = 0; m < M; ++m) {
        const float4 xv = *reinterpret_cast<const float4*>(&x_lds[m][i]);
        SIGACC(p0, xv.x, pn[m], pd[m]);
        SIGACC(p1, xv.y, pn[m], pd[m]);
        SIGACC(p2, xv.z, pn[m], pd[m]);
        SIGACC(p3, xv.w, pn[m], pd[m]);
      }
    }
#pragma unroll
    for (int m = 0; m < M; ++m) part[s][m][j] = make_float2(pn[m], pd[m]);
    __syncthreads();
#pragma unroll
    for (int m = 0; m < M; ++m) {
      float n = 0.f, d = 0.f;
#pragma unroll
      for (int t2 = 0; t2 < S; ++t2) { const float2 f = part[t2][m][j]; n += f.x; d += f.y; }
      wns[m] = n; wds[m] = d;
    }
  }

  float sv[M];
#pragma unroll
  for (int m = 0; m < M; ++m) sv[m] = states[(b0 + m) * U + j];

  float vj[M];
  for (int sde = 0; sde < SDE; ++sde) {
#pragma unroll
    for (int m = 0; m < M; ++m) vj[m] = sv[m];
    if (s == 0) {
#pragma unroll
      for (int m = 0; m < M; ++m) v_lds[m][j] = sv[m];
    }
    __syncthreads();  // v_lds publish + part reuse hazard

    for (int ode = 0; ode < ODE; ++ode) {
      float pn[M], pd[M];
#pragma unroll
      for (int m = 0; m < M; ++m) { pn[m] = 0.f; pd[m] = 0.f; }
      // main i-sweep: ZERO global loads — params from registers (static
      // indices via full unroll, rule #20), v via LDS broadcast.
#pragma unroll
      for (int kk = 0; kk < RPT; kk += 4) {
        const int i = s * RPT + kk;
#pragma unroll
        for (int m = 0; m < M; ++m) {
          const float4 vv = *reinterpret_cast<const float4*>(&v_lds[m][i]);
          SIGACC(P[kk + 0], vv.x, pn[m], pd[m]);
          SIGACC(P[kk + 1], vv.y, pn[m], pd[m]);
          SIGACC(P[kk + 2], vv.z, pn[m], pd[m]);
          SIGACC(P[kk + 3], vv.w, pn[m], pd[m]);
        }
      }
#pragma unroll
      for (int m = 0; m < M; ++m) part[s][m][j] = make_float2(pn[m], pd[m]);
      __syncthreads();
      // every s-replica computes the identical v update (avoids a broadcast)
#pragma unroll
      for (int m = 0; m < M; ++m) {
        float n = wns[m], d = wds[m];
#pragma unroll
        for (int t2 = 0; t2 < S; ++t2) { const float2 f = part[t2][m][j]; n += f.x; d += f.y; }
        const float den = cg + d;
        float r = RCP(den);
        r = r * (2.0f - den * r);            // one Newton step on the feedback path
        vj[m] = (fmaf(cm, vj[m], gv) + n) * r;
      }
      if (s == 0) {
#pragma unroll
        for (int m = 0; m < M; ++m) v_lds[m][j] = vj[m];
      }
      __syncthreads();  // v_lds ready; part free for rewrite
    }
#pragma unroll
    for (int m = 0; m < M; ++m) sv[m] += vj[m];
  }

  if (s == 0) {
#pragma unroll
    for (int m = 0; m < M; ++m) out[(b0 + m) * U + j] = sv[m];
  }
}

extern "C" void kernel_launch(void* const* d_in, const int* in_sizes, int n_in,
                              void* d_out, int out_size, void* d_ws, size_t ws_size,
                              hipStream_t stream) {
  const float* inputs = (const float*)d_in[0];
  const float* states = (const float*)d_in[1];
  const float* iw     = (const float*)d_in[2];
  const float* ibias  = (const float*)d_in[3];
  const float* smu    = (const float*)d_in[4];
  const float* ssig   = (const float*)d_in[5];
  const float* sW     = (const float*)d_in[6];
  const float* serev  = (const float*)d_in[7];
  const float* mu     = (const float*)d_in[8];
  const float* sigma  = (const float*)d_in[9];
  const float* W      = (const float*)d_in[10];
  const float* erev   = (const float*)d_in[11];
  const float* vleak  = (const float*)d_in[12];
  const float* gleak  = (const float*)d_in[13];
  const float* cmt    = (const float*)d_in[14];
  float* out = (float*)d_out;

  // d_ws layout: packed main params (256 KB) then packed sensory params (128 KB)
  float4* pp = (float4*)d_ws;
  float4* ps = pp + U * U;

  const int packN = U * U + I * U;  // 24576
  pack_params<<<(packN + 255) / 256, 256, 0, stream>>>(
      mu, sigma, W, erev, smu, ssig, sW, serev, pp, ps);
  ltc_kernel<<<B / M, BLK, 0, stream>>>(
      pp, ps, inputs, states, iw, ibias, vleak, gleak, cmt, out);
}